// Round 2
// baseline (2911.074 us; speedup 1.0000x reference)
//
#include <hip/hip_runtime.h>
#include <math.h>

// Problem constants (from reference): B=32768, U=256, F=256, H=4U=1024
#define B_N 32768
#define U_N 256
#define H_N 1024
#define LR_C 0.01f
#define EPS_C 1e-3f

__device__ __forceinline__ float gelu_f(float x) {
    return 0.5f * x * (1.0f + erff(x * 0.7071067811865475f));
}
__device__ __forceinline__ float dgelu_f(float x) {
    float c = 0.5f * (1.0f + erff(x * 0.7071067811865475f));
    float p = 0.3989422804014327f * expf(-0.5f * x * x);
    return c + x * p;
}

#define EPI_NONE 0
#define EPI_GELU 1
#define EPI_DGELU 2
#define EPI_ADDS 3

// C[M,N] = op_epi( opA(A) @ opB(B) + bias )
// ACONCAT: A row = [A(256) | A2(256)], K=512. AGELU: gelu applied to A elements.
// BTRANS: B operand is W^T with W row-major [N, K] (row stride K).
// EPI_DGELU: C = acc * dgelu(X)   (bias null; X may alias C — element-local)
// EPI_ADDS : C = acc + bias + 0.1*X
template<int ACONCAT, int AGELU, int BTRANS, int EPI>
__global__ __launch_bounds__(256)
void gemm_k(const float* __restrict__ A, const float* __restrict__ A2,
            const float* __restrict__ Bm, const float* __restrict__ bias,
            const float* X, float* C,
            int M, int N, int K)
{
    __shared__ float As[16][68];   // row stride 272B = 16*17 -> float4 LDS ops stay 16B-aligned
    __shared__ float Bs[16][68];
    const int tid = threadIdx.x;
    const int m0 = blockIdx.x * 64;
    const int n0 = blockIdx.y * 64;
    const int tx = tid & 15, ty = tid >> 4;
    const int a_r = tid >> 2;          // 0..63
    const int a_c = (tid & 3) << 2;    // 0,4,8,12
    const int b_r = tid >> 4;          // 0..15
    const int b_c = (tid & 15) << 2;   // 0..60
    float acc[4][4] = {};

    for (int k0 = 0; k0 < K; k0 += 16) {
        // A tile -> As[k][m] (transposed store)
        {
            const int ar = m0 + a_r;
            const int ak = k0 + a_c;
            const float* ap;
            if (ACONCAT) {
                ap = (ak < 256) ? (A + (size_t)ar * 256 + ak)
                                : (A2 + (size_t)ar * 256 + (ak - 256));
            } else {
                ap = A + (size_t)ar * K + ak;
            }
            float4 av = *(const float4*)ap;
            if (AGELU) { av.x = gelu_f(av.x); av.y = gelu_f(av.y);
                         av.z = gelu_f(av.z); av.w = gelu_f(av.w); }
            As[a_c + 0][a_r] = av.x;
            As[a_c + 1][a_r] = av.y;
            As[a_c + 2][a_r] = av.z;
            As[a_c + 3][a_r] = av.w;
        }
        // B tile -> Bs[k][n]
        if (BTRANS) {
            float4 bv = *(const float4*)(Bm + (size_t)(n0 + a_r) * K + (k0 + a_c));
            Bs[a_c + 0][a_r] = bv.x;
            Bs[a_c + 1][a_r] = bv.y;
            Bs[a_c + 2][a_r] = bv.z;
            Bs[a_c + 3][a_r] = bv.w;
        } else {
            float4 bv = *(const float4*)(Bm + (size_t)(k0 + b_r) * N + (n0 + b_c));
            *(float4*)&Bs[b_r][b_c] = bv;
        }
        __syncthreads();
        #pragma unroll
        for (int kk = 0; kk < 16; kk++) {
            float4 a4 = *(const float4*)&As[kk][ty << 2];
            float4 b4 = *(const float4*)&Bs[kk][tx << 2];
            float ar4[4] = {a4.x, a4.y, a4.z, a4.w};
            float br4[4] = {b4.x, b4.y, b4.z, b4.w};
            #pragma unroll
            for (int i = 0; i < 4; i++)
                #pragma unroll
                for (int j = 0; j < 4; j++)
                    acc[i][j] += ar4[i] * br4[j];
        }
        __syncthreads();
    }

    float bvals[4] = {0.f, 0.f, 0.f, 0.f};
    if (bias != nullptr) {
        float4 t = *(const float4*)(bias + n0 + (tx << 2));
        bvals[0] = t.x; bvals[1] = t.y; bvals[2] = t.z; bvals[3] = t.w;
    }
    #pragma unroll
    for (int i = 0; i < 4; i++) {
        const int row = m0 + (ty << 2) + i;
        const size_t off = (size_t)row * N + n0 + (tx << 2);
        float vals[4];
        #pragma unroll
        for (int j = 0; j < 4; j++) {
            float c = acc[i][j] + bvals[j];
            if (EPI == EPI_GELU)       c = gelu_f(c);
            else if (EPI == EPI_DGELU) c = c * dgelu_f(X[off + j]);
            else if (EPI == EPI_ADDS)  c = c + 0.1f * X[off + j];
            vals[j] = c;
        }
        float4 o; o.x = vals[0]; o.y = vals[1]; o.z = vals[2]; o.w = vals[3];
        *(float4*)(C + off) = o;
    }
}

// C[M,N] += sum_k opA(A[k,m]) * B[k,n] over this block's K-chunk (split-K, atomics)
// A row-major [rows, M] (stride M), B row-major [rows, N] (stride N)
template<int AGELU>
__global__ __launch_bounds__(256)
void gemm_atb_k(const float* __restrict__ A, const float* __restrict__ Bm,
                float* C, int M, int N, int CH)
{
    __shared__ float As[16][68];
    __shared__ float Bs[16][68];
    const int tid = threadIdx.x;
    const int m0 = blockIdx.x * 64;
    const int n0 = blockIdx.y * 64;
    const int kbeg = blockIdx.z * CH;
    const int tx = tid & 15, ty = tid >> 4;
    const int l_k = tid >> 4;        // 0..15
    const int l_c = (tid & 15) << 2; // 0..60
    float acc[4][4] = {};

    for (int k0 = kbeg; k0 < kbeg + CH; k0 += 16) {
        float4 av = *(const float4*)(A + (size_t)(k0 + l_k) * M + m0 + l_c);
        if (AGELU) { av.x = gelu_f(av.x); av.y = gelu_f(av.y);
                     av.z = gelu_f(av.z); av.w = gelu_f(av.w); }
        *(float4*)&As[l_k][l_c] = av;
        float4 bv = *(const float4*)(Bm + (size_t)(k0 + l_k) * N + n0 + l_c);
        *(float4*)&Bs[l_k][l_c] = bv;
        __syncthreads();
        #pragma unroll
        for (int kk = 0; kk < 16; kk++) {
            float4 a4 = *(const float4*)&As[kk][ty << 2];
            float4 b4 = *(const float4*)&Bs[kk][tx << 2];
            float ar4[4] = {a4.x, a4.y, a4.z, a4.w};
            float br4[4] = {b4.x, b4.y, b4.z, b4.w};
            #pragma unroll
            for (int i = 0; i < 4; i++)
                #pragma unroll
                for (int j = 0; j < 4; j++)
                    acc[i][j] += ar4[i] * br4[j];
        }
        __syncthreads();
    }
    #pragma unroll
    for (int i = 0; i < 4; i++) {
        const int row = m0 + (ty << 2) + i;
        #pragma unroll
        for (int j = 0; j < 4; j++)
            atomicAdd(&C[(size_t)row * N + n0 + (tx << 2) + j], acc[i][j]);
    }
}

__global__ __launch_bounds__(256)
void colsum_k(const float* __restrict__ A, float* out, int N, int rows)
{
    const int col = blockIdx.x * 256 + threadIdx.x;
    const int r0 = blockIdx.y * rows;
    float s = 0.f;
    for (int r = 0; r < rows; r++) s += A[(size_t)(r0 + r) * N + col];
    atomicAdd(&out[col], s);
}

// LayerNorm forward + dL/dr0 (row-wise; dr0 may alias r0: one wave owns a row,
// all reads happen before writes inside the thread)
__global__ __launch_bounds__(256)
void ln_fb_k(const float* r0, const float* __restrict__ phi,
             const float* __restrict__ gamma, const float* __restrict__ beta,
             float* recon, float* dr0)
{
    const int lane = threadIdx.x & 63;
    const int wv = threadIdx.x >> 6;
    const int row = blockIdx.x * 4 + wv;
    const size_t base = (size_t)row * U_N + (lane << 2);

    float4 xv = *(const float4*)(r0 + base);
    float s  = xv.x + xv.y + xv.z + xv.w;
    float sq = xv.x * xv.x + xv.y * xv.y + xv.z * xv.z + xv.w * xv.w;
    #pragma unroll
    for (int o = 32; o > 0; o >>= 1) { s += __shfl_xor(s, o); sq += __shfl_xor(sq, o); }
    const float m   = s * (1.0f / U_N);
    const float var = sq * (1.0f / U_N) - m * m;   // biased var (jnp.var default)
    const float inv = rsqrtf(var + EPS_C);

    float4 gv = *(const float4*)(gamma + (lane << 2));
    float4 bv = *(const float4*)(beta + (lane << 2));
    float4 pv = *(const float4*)(phi + base);
    float xs[4] = {xv.x, xv.y, xv.z, xv.w};
    float gs[4] = {gv.x, gv.y, gv.z, gv.w};
    float bs[4] = {bv.x, bv.y, bv.z, bv.w};
    float ps[4] = {pv.x, pv.y, pv.z, pv.w};
    float rh[4], dh[4], rc[4];
    float s1 = 0.f, s2 = 0.f;
    const float gscale = 2.0f / ((float)B_N * (float)U_N);   // d(mean sq err)/dr
    #pragma unroll
    for (int j = 0; j < 4; j++) {
        rh[j] = (xs[j] - m) * inv;
        rc[j] = rh[j] * gs[j] + bs[j];
        float g2 = gscale * (rc[j] - ps[j]);
        dh[j] = g2 * gs[j];
        s1 += dh[j];
        s2 += dh[j] * rh[j];
    }
    #pragma unroll
    for (int o = 32; o > 0; o >>= 1) { s1 += __shfl_xor(s1, o); s2 += __shfl_xor(s2, o); }
    const float mu1 = s1 * (1.0f / U_N);
    const float mu2 = s2 * (1.0f / U_N);
    float4 ov, dv;
    ov.x = rc[0]; ov.y = rc[1]; ov.z = rc[2]; ov.w = rc[3];
    dv.x = inv * (dh[0] - mu1 - rh[0] * mu2);
    dv.y = inv * (dh[1] - mu1 - rh[1] * mu2);
    dv.z = inv * (dh[2] - mu1 - rh[2] * mu2);
    dv.w = inv * (dh[3] - mu1 - rh[3] * mu2);
    *(float4*)(recon + base) = ov;
    *(float4*)(dr0 + base) = dv;
}

__global__ __launch_bounds__(256)
void wupdate_k(const float* __restrict__ W1, const float* __restrict__ b1,
               const float* __restrict__ W2, const float* __restrict__ b2,
               const float* __restrict__ dW1, const float* __restrict__ db1,
               const float* __restrict__ dW2, const float* __restrict__ db2,
               float* __restrict__ W1u, float* __restrict__ b1u,
               float* __restrict__ W2u, float* __restrict__ b2u)
{
    const int i = blockIdx.x * 256 + threadIdx.x;
    if (i < U_N * H_N) {
        W1u[i] = W1[i] - LR_C * dW1[i];
        W2u[i] = W2[i] - LR_C * dW2[i];
    }
    if (i < H_N) b1u[i] = b1[i] - LR_C * db1[i];
    if (i < U_N) b2u[i] = b2[i] - LR_C * db2[i];
}

extern "C" void kernel_launch(void* const* d_in, const int* in_sizes, int n_in,
                              void* d_out, int out_size, void* d_ws, size_t ws_size,
                              hipStream_t stream)
{
    const float* x      = (const float*)d_in[0];
    const float* h_prev = (const float*)d_in[1];
    const float* W_phi  = (const float*)d_in[2];
    const float* b_phi  = (const float*)d_in[3];
    const float* W_psi  = (const float*)d_in[4];
    const float* b_psi  = (const float*)d_in[5];
    const float* W1     = (const float*)d_in[6];
    const float* b1     = (const float*)d_in[7];
    const float* W2     = (const float*)d_in[8];
    const float* b2     = (const float*)d_in[9];
    const float* W_g    = (const float*)d_in[10];
    const float* g_bias = (const float*)d_in[11];
    const float* gamma  = (const float*)d_in[12];
    const float* beta   = (const float*)d_in[13];
    const float* W_h    = (const float*)d_in[14];
    const float* h_bias = (const float*)d_in[15];
    float* out = (float*)d_out;

    // ---- workspace plan: chunk the batch so we fit ws_size ----
    // persistent: phi [B,U], recon [B,U]; per-chunk: a1 [Bc,H], e/r0/de [Bc,U];
    // weights: dW1,db1,dW2,db2,W1u,b1u,W2u,b2u
    const size_t BU = (size_t)B_N * U_N;
    const size_t Wfl = 4 * (size_t)U_N * H_N + 2 * H_N + 2 * U_N;
    int G = 1;
    while (G < 64) {
        size_t Bc = (size_t)B_N / G;
        size_t need = (2 * BU + Bc * H_N + 3 * Bc * U_N + Wfl) * sizeof(float);
        if (need <= ws_size) break;
        G *= 2;
    }
    const int Bc = B_N / G;          // multiple of 64 for all G<=64
    const int CH = Bc / 8;           // split-K rows per z-block (multiple of 16)

    float* ws    = (float*)d_ws;
    float* phi   = ws;                                   // [B,U]
    float* recon = phi   + BU;                           // [B,U]
    float* a1b   = recon + BU;                           // [Bc,H]: a1 -> da -> h2
    float* eb    = a1b   + (size_t)Bc * H_N;             // [Bc,U]: e -> feat
    float* r0b   = eb    + (size_t)Bc * U_N;             // [Bc,U]: r0 -> dr0 -> psi
    float* deb   = r0b   + (size_t)Bc * U_N;             // [Bc,U]: de
    float* dW1   = deb   + (size_t)Bc * U_N;             // [U,H]
    float* db1   = dW1 + U_N * H_N;                      // [H]
    float* dW2   = db1 + H_N;                            // [H,U]
    float* db2   = dW2 + U_N * H_N;                      // [U]
    float* W1u   = db2 + U_N;
    float* b1u   = W1u + U_N * H_N;
    float* W2u   = b1u + H_N;
    float* b2u   = W2u + U_N * H_N;

    // zero grad accumulators (dW1, db1, dW2, db2 contiguous)
    hipMemsetAsync(dW1, 0, (size_t)(2 * U_N * H_N + H_N + U_N) * sizeof(float), stream);

    dim3 blk(256);
    // phi = [x|h_prev] @ W_phi + b_phi   (full batch, persistent)
    gemm_k<1,0,0,EPI_NONE><<<dim3(B_N/64, U_N/64), blk, 0, stream>>>(
        x, h_prev, W_phi, b_phi, nullptr, phi, B_N, U_N, 512);

    // ---- Phase A: inner-loss forward + backward, chunked over rows ----
    for (int c = 0; c < G; c++) {
        const size_t r0off = (size_t)c * Bc;
        const float* phic = phi + r0off * U_N;
        float* reconc = recon + r0off * U_N;
        // a1 = phi_c @ W1 + b1
        gemm_k<0,0,0,EPI_NONE><<<dim3(Bc/64, H_N/64), blk, 0, stream>>>(
            phic, nullptr, W1, b1, nullptr, a1b, Bc, H_N, U_N);
        // e = gelu(a1) @ W2 + b2
        gemm_k<0,1,0,EPI_NONE><<<dim3(Bc/64, U_N/64), blk, 0, stream>>>(
            a1b, nullptr, W2, b2, nullptr, eb, Bc, U_N, H_N);
        // r0 = e @ W_g + g_bias
        gemm_k<0,0,0,EPI_NONE><<<dim3(Bc/64, U_N/64), blk, 0, stream>>>(
            eb, nullptr, W_g, g_bias, nullptr, r0b, Bc, U_N, U_N);
        // recon_c = LN(r0); dr0 = LN-backward (in-place over r0b)
        ln_fb_k<<<dim3(Bc/4), blk, 0, stream>>>(r0b, phic, gamma, beta, reconc, r0b);
        // de = dr0 @ W_g^T
        gemm_k<0,0,1,EPI_NONE><<<dim3(Bc/64, U_N/64), blk, 0, stream>>>(
            r0b, nullptr, W_g, nullptr, nullptr, deb, Bc, U_N, U_N);
        // dW2 += gelu(a1)^T @ de ; db2 += colsum(de)
        gemm_atb_k<1><<<dim3(H_N/64, U_N/64, Bc/CH), blk, 0, stream>>>(
            a1b, deb, dW2, H_N, U_N, CH);
        colsum_k<<<dim3(U_N/256, Bc/128), blk, 0, stream>>>(deb, db2, U_N, 128);
        // da = (de @ W2^T) * dgelu(a1)   (element-local, in-place over a1b)
        gemm_k<0,0,1,EPI_DGELU><<<dim3(Bc/64, H_N/64), blk, 0, stream>>>(
            deb, nullptr, W2, nullptr, a1b, a1b, Bc, H_N, U_N);
        // dW1 += phi_c^T @ da ; db1 += colsum(da)
        gemm_atb_k<0><<<dim3(U_N/64, H_N/64, Bc/CH), blk, 0, stream>>>(
            phic, a1b, dW1, U_N, H_N, CH);
        colsum_k<<<dim3(H_N/256, Bc/128), blk, 0, stream>>>(a1b, db1, H_N, 128);
    }

    // ---- Phase B: params' = params - LR * grads ----
    wupdate_k<<<dim3((U_N*H_N)/256), blk, 0, stream>>>(
        W1, b1, W2, b2, dW1, db1, dW2, db2, W1u, b1u, W2u, b2u);

    // ---- Phase C: out = (enc'(psi) + 0.1*recon) @ W_h + h_bias, chunked ----
    for (int c = 0; c < G; c++) {
        const size_t r0off = (size_t)c * Bc;
        // psi_c = [x|h_prev]_c @ W_psi + b_psi   (into r0b)
        gemm_k<1,0,0,EPI_NONE><<<dim3(Bc/64, U_N/64), blk, 0, stream>>>(
            x + r0off * 256, h_prev + r0off * U_N, W_psi, b_psi, nullptr, r0b, Bc, U_N, 512);
        // h2 = gelu(psi @ W1' + b1')   (into a1b)
        gemm_k<0,0,0,EPI_GELU><<<dim3(Bc/64, H_N/64), blk, 0, stream>>>(
            r0b, nullptr, W1u, b1u, nullptr, a1b, Bc, H_N, U_N);
        // feat = h2 @ W2' + b2' + 0.1*recon_c   (into eb)
        gemm_k<0,0,0,EPI_ADDS><<<dim3(Bc/64, U_N/64), blk, 0, stream>>>(
            a1b, nullptr, W2u, b2u, recon + r0off * U_N, eb, Bc, U_N, H_N);
        // out_c = feat @ W_h + h_bias
        gemm_k<0,0,0,EPI_NONE><<<dim3(Bc/64, U_N/64), blk, 0, stream>>>(
            eb, nullptr, W_h, h_bias, nullptr, out + r0off * U_N, Bc, U_N, U_N);
    }
}

// Round 4
// 1630.813 us; speedup vs baseline: 1.7850x; 1.7850x over previous
//
#include <hip/hip_runtime.h>
#include <math.h>

#define B_N 32768
#define U_N 256
#define H_N 1024
#define LR_C 0.01f
#define EPS_C 1e-3f

typedef unsigned short ushort_t;
typedef unsigned int uint_t;
using frag8 = __attribute__((ext_vector_type(8))) short;   // 8 bf16 = 4 VGPR
using f32x4 = __attribute__((ext_vector_type(4))) float;   // MFMA acc

__device__ __forceinline__ float gelu_f(float x) {
    return 0.5f * x * (1.0f + erff(x * 0.7071067811865475f));
}
__device__ __forceinline__ float dgelu_f(float x) {
    float c = 0.5f * (1.0f + erff(x * 0.7071067811865475f));
    float p = 0.3989422804014327f * expf(-0.5f * x * x);
    return c + x * p;
}

// fp32 -> (hi, lo) bf16 pair. hi = truncation (residual exact), lo = RNE(residual).
__device__ __forceinline__ void splitf(float v, ushort_t& h, ushort_t& l) {
    uint_t u = __float_as_uint(v);
    h = (ushort_t)(u >> 16);
    float r = v - __uint_as_float(u & 0xFFFF0000u);
    uint_t ru = __float_as_uint(r);
    l = (ushort_t)((ru + 0x7FFFu + ((ru >> 16) & 1u)) >> 16);
}

#define EPI_NONE 0
#define EPI_GELU 1
#define EPI_DGELU 2
#define EPI_ADDS 3

// ---------------------------------------------------------------------------
// MFMA GEMM: C[M,N] = epi( A[M,K] @ B[K,N] + bias ), B given as BT = B^T [N,K]
// pre-split into bf16 hi/lo planes. A fp32, split in staging. 128x128 tile,
// 4 waves x (4x4) 16x16x32 MFMA frags, 3 passes (hh, hl, lh).
// ---------------------------------------------------------------------------
template<int ACONCAT, int AGELU, int EPI>
__global__ __launch_bounds__(256)
void mgemm_k(const float* A, const float* A2,
             const ushort_t* __restrict__ BTh, const ushort_t* __restrict__ BTl,
             const float* __restrict__ bias, const float* X, float* C,
             int M, int N, int K)
{
    __shared__ ushort_t Ah[128 * 40], Al[128 * 40];   // [row][k], pitch 40 (80B)
    __shared__ ushort_t Bh[128 * 40], Bl[128 * 40];   // [col][k]
    const int tid = threadIdx.x;
    const int m0 = blockIdx.x * 128, n0 = blockIdx.y * 128;
    const int lane = tid & 63, w = tid >> 6;
    const int wm = (w & 1) * 64, wn = (w >> 1) * 64;
    const int fr = lane & 15, fq = lane >> 4;
    const int sr = tid >> 1;               // staging row 0..127
    const int sk = (tid & 1) * 16;         // staging k offset 0/16

    f32x4 acc[4][4];
    #pragma unroll
    for (int i = 0; i < 4; i++)
        #pragma unroll
        for (int j = 0; j < 4; j++) acc[i][j] = (f32x4){0.f, 0.f, 0.f, 0.f};

    for (int k0 = 0; k0 < K; k0 += 32) {
        // ---- stage A: 128x32 fp32 -> hi/lo bf16 (16 ushorts per thread) ----
        #pragma unroll
        for (int g = 0; g < 2; g++) {
            uint4 qh, qa;
            uint_t ph[4], pl[4];
            #pragma unroll
            for (int c = 0; c < 2; c++) {
                const int ak = k0 + sk + g * 8 + c * 4;
                const float* ap;
                if (ACONCAT) ap = (ak < 256) ? (A + (size_t)(m0 + sr) * 256 + ak)
                                             : (A2 + (size_t)(m0 + sr) * 256 + (ak - 256));
                else         ap = A + (size_t)(m0 + sr) * K + ak;
                float4 v = *(const float4*)ap;
                if (AGELU) { v.x = gelu_f(v.x); v.y = gelu_f(v.y);
                             v.z = gelu_f(v.z); v.w = gelu_f(v.w); }
                ushort_t h0,h1,h2,h3,l0,l1,l2,l3;
                splitf(v.x,h0,l0); splitf(v.y,h1,l1); splitf(v.z,h2,l2); splitf(v.w,h3,l3);
                ph[c*2]   = (uint_t)h0 | ((uint_t)h1 << 16);
                ph[c*2+1] = (uint_t)h2 | ((uint_t)h3 << 16);
                pl[c*2]   = (uint_t)l0 | ((uint_t)l1 << 16);
                pl[c*2+1] = (uint_t)l2 | ((uint_t)l3 << 16);
            }
            qh.x = ph[0]; qh.y = ph[1]; qh.z = ph[2]; qh.w = ph[3];
            qa.x = pl[0]; qa.y = pl[1]; qa.z = pl[2]; qa.w = pl[3];
            *(uint4*)&Ah[sr * 40 + sk + g * 8] = qh;
            *(uint4*)&Al[sr * 40 + sk + g * 8] = qa;
        }
        // ---- stage B: copy pre-split bf16 planes (16 ushorts per thread) ----
        {
            const size_t bo = (size_t)(n0 + sr) * K + k0 + sk;
            *(uint4*)&Bh[sr * 40 + sk]     = *(const uint4*)&BTh[bo];
            *(uint4*)&Bh[sr * 40 + sk + 8] = *(const uint4*)&BTh[bo + 8];
            *(uint4*)&Bl[sr * 40 + sk]     = *(const uint4*)&BTl[bo];
            *(uint4*)&Bl[sr * 40 + sk + 8] = *(const uint4*)&BTl[bo + 8];
        }
        __syncthreads();

        frag8 afh[4], afl[4], bfh[4], bfl[4];
        #pragma unroll
        for (int i = 0; i < 4; i++) {
            const int ar = wm + i * 16 + fr;
            afh[i] = *(frag8*)&Ah[ar * 40 + fq * 8];
            afl[i] = *(frag8*)&Al[ar * 40 + fq * 8];
        }
        #pragma unroll
        for (int j = 0; j < 4; j++) {
            const int br = wn + j * 16 + fr;
            bfh[j] = *(frag8*)&Bh[br * 40 + fq * 8];
            bfl[j] = *(frag8*)&Bl[br * 40 + fq * 8];
        }
        #pragma unroll
        for (int i = 0; i < 4; i++)
            #pragma unroll
            for (int j = 0; j < 4; j++) {
                acc[i][j] = __builtin_amdgcn_mfma_f32_16x16x32_bf16(afh[i], bfh[j], acc[i][j], 0, 0, 0);
                acc[i][j] = __builtin_amdgcn_mfma_f32_16x16x32_bf16(afh[i], bfl[j], acc[i][j], 0, 0, 0);
                acc[i][j] = __builtin_amdgcn_mfma_f32_16x16x32_bf16(afl[i], bfh[j], acc[i][j], 0, 0, 0);
            }
        __syncthreads();
    }

    float bv[4] = {0.f, 0.f, 0.f, 0.f};
    if (bias != nullptr)
        #pragma unroll
        for (int j = 0; j < 4; j++) bv[j] = bias[n0 + wn + j * 16 + fr];
    #pragma unroll
    for (int i = 0; i < 4; i++)
        #pragma unroll
        for (int j = 0; j < 4; j++) {
            const int col = n0 + wn + j * 16 + fr;
            #pragma unroll
            for (int r = 0; r < 4; r++) {
                const int row = m0 + wm + i * 16 + fq * 4 + r;
                const size_t off = (size_t)row * N + col;
                float c = acc[i][j][r] + bv[j];
                if (EPI == EPI_GELU)       c = gelu_f(c);
                else if (EPI == EPI_DGELU) c = c * dgelu_f(X[off]);
                else if (EPI == EPI_ADDS)  c = c + 0.1f * X[off];
                C[off] = c;
            }
        }
}

// ---------------------------------------------------------------------------
// MFMA TN GEMM (weight grads): C[M,N] += sum_k A[k,m] * B[k,n] over K-chunk.
// A [rows,M] fp32, B [rows,N] fp32; batch-pair packed transpose staging.
// ---------------------------------------------------------------------------
template<int AGELU>
__global__ __launch_bounds__(256)
void mgemm_atb_k(const float* A, const float* Bg, float* C,
                 int M, int N, int CH)
{
    __shared__ ushort_t Ah[128 * 40], Al[128 * 40];
    __shared__ ushort_t Bh[128 * 40], Bl[128 * 40];
    const int tid = threadIdx.x;
    const int m0 = blockIdx.x * 128, n0 = blockIdx.y * 128;
    const int kbeg = blockIdx.z * CH;
    const int lane = tid & 63, w = tid >> 6;
    const int wm = (w & 1) * 64, wn = (w >> 1) * 64;
    const int fr = lane & 15, fq = lane >> 4;
    const int c0 = (tid & 63) * 2;         // 2 cols per thread
    const int p0 = (tid >> 6) * 4;         // 4 batch-pairs per thread

    f32x4 acc[4][4];
    #pragma unroll
    for (int i = 0; i < 4; i++)
        #pragma unroll
        for (int j = 0; j < 4; j++) acc[i][j] = (f32x4){0.f, 0.f, 0.f, 0.f};

    for (int k0 = kbeg; k0 < kbeg + CH; k0 += 32) {
        // ---- stage A^T tile ----
        {
            uint4 qh0, ql0, qh1, ql1;
            uint_t* h0 = (uint_t*)&qh0; uint_t* l0 = (uint_t*)&ql0;
            uint_t* h1 = (uint_t*)&qh1; uint_t* l1 = (uint_t*)&ql1;
            #pragma unroll
            for (int d = 0; d < 4; d++) {
                float2 va = *(const float2*)(A + (size_t)(k0 + p0 * 2 + 2 * d) * M + m0 + c0);
                float2 vb = *(const float2*)(A + (size_t)(k0 + p0 * 2 + 2 * d + 1) * M + m0 + c0);
                if (AGELU) { va.x = gelu_f(va.x); va.y = gelu_f(va.y);
                             vb.x = gelu_f(vb.x); vb.y = gelu_f(vb.y); }
                ushort_t ha,la,hb,lb;
                splitf(va.x, ha, la); splitf(vb.x, hb, lb);
                h0[d] = (uint_t)ha | ((uint_t)hb << 16);
                l0[d] = (uint_t)la | ((uint_t)lb << 16);
                splitf(va.y, ha, la); splitf(vb.y, hb, lb);
                h1[d] = (uint_t)ha | ((uint_t)hb << 16);
                l1[d] = (uint_t)la | ((uint_t)lb << 16);
            }
            *(uint4*)&Ah[c0 * 40 + p0 * 2]       = qh0;
            *(uint4*)&Al[c0 * 40 + p0 * 2]       = ql0;
            *(uint4*)&Ah[(c0 + 1) * 40 + p0 * 2] = qh1;
            *(uint4*)&Al[(c0 + 1) * 40 + p0 * 2] = ql1;
        }
        // ---- stage B^T tile ----
        {
            uint4 qh0, ql0, qh1, ql1;
            uint_t* h0 = (uint_t*)&qh0; uint_t* l0 = (uint_t*)&ql0;
            uint_t* h1 = (uint_t*)&qh1; uint_t* l1 = (uint_t*)&ql1;
            #pragma unroll
            for (int d = 0; d < 4; d++) {
                float2 va = *(const float2*)(Bg + (size_t)(k0 + p0 * 2 + 2 * d) * N + n0 + c0);
                float2 vb = *(const float2*)(Bg + (size_t)(k0 + p0 * 2 + 2 * d + 1) * N + n0 + c0);
                ushort_t ha,la,hb,lb;
                splitf(va.x, ha, la); splitf(vb.x, hb, lb);
                h0[d] = (uint_t)ha | ((uint_t)hb << 16);
                l0[d] = (uint_t)la | ((uint_t)lb << 16);
                splitf(va.y, ha, la); splitf(vb.y, hb, lb);
                h1[d] = (uint_t)ha | ((uint_t)hb << 16);
                l1[d] = (uint_t)la | ((uint_t)lb << 16);
            }
            *(uint4*)&Bh[c0 * 40 + p0 * 2]       = qh0;
            *(uint4*)&Bl[c0 * 40 + p0 * 2]       = ql0;
            *(uint4*)&Bh[(c0 + 1) * 40 + p0 * 2] = qh1;
            *(uint4*)&Bl[(c0 + 1) * 40 + p0 * 2] = ql1;
        }
        __syncthreads();

        frag8 afh[4], afl[4], bfh[4], bfl[4];
        #pragma unroll
        for (int i = 0; i < 4; i++) {
            const int ar = wm + i * 16 + fr;
            afh[i] = *(frag8*)&Ah[ar * 40 + fq * 8];
            afl[i] = *(frag8*)&Al[ar * 40 + fq * 8];
        }
        #pragma unroll
        for (int j = 0; j < 4; j++) {
            const int br = wn + j * 16 + fr;
            bfh[j] = *(frag8*)&Bh[br * 40 + fq * 8];
            bfl[j] = *(frag8*)&Bl[br * 40 + fq * 8];
        }
        #pragma unroll
        for (int i = 0; i < 4; i++)
            #pragma unroll
            for (int j = 0; j < 4; j++) {
                acc[i][j] = __builtin_amdgcn_mfma_f32_16x16x32_bf16(afh[i], bfh[j], acc[i][j], 0, 0, 0);
                acc[i][j] = __builtin_amdgcn_mfma_f32_16x16x32_bf16(afh[i], bfl[j], acc[i][j], 0, 0, 0);
                acc[i][j] = __builtin_amdgcn_mfma_f32_16x16x32_bf16(afl[i], bfh[j], acc[i][j], 0, 0, 0);
            }
        __syncthreads();
    }
    #pragma unroll
    for (int i = 0; i < 4; i++)
        #pragma unroll
        for (int j = 0; j < 4; j++) {
            const int col = n0 + wn + j * 16 + fr;
            #pragma unroll
            for (int r = 0; r < 4; r++) {
                const int row = m0 + wm + i * 16 + fq * 4 + r;
                atomicAdd(&C[(size_t)row * N + col], acc[i][j][r]);
            }
        }
}

// transpose + split: W [R,C] fp32 -> Th/Tl [C,R] bf16 planes
__global__ __launch_bounds__(256)
void tsplit_k(const float* __restrict__ W, ushort_t* __restrict__ Th,
              ushort_t* __restrict__ Tl, int R, int C)
{
    __shared__ float t[64][65];
    const int tid = threadIdx.x;
    const int R0 = blockIdx.x * 64, C0 = blockIdx.y * 64;
    const int c = tid & 63, rb = (tid >> 6) * 16;
    for (int i = 0; i < 16; i++)
        t[rb + i][c] = W[(size_t)(R0 + rb + i) * C + C0 + c];
    __syncthreads();
    const int orr = tid & 63, ob = (tid >> 6) * 16;
    for (int i = 0; i < 16; i++) {
        const int oc = ob + i;
        ushort_t h, l;
        splitf(t[orr][oc], h, l);
        Th[(size_t)(C0 + oc) * R + R0 + orr] = h;
        Tl[(size_t)(C0 + oc) * R + R0 + orr] = l;
    }
}

// transpose + SGD update + split: (W - LR*dW) [R,C] -> Th/Tl [C,R]
__global__ __launch_bounds__(256)
void tupd_k(const float* __restrict__ W, const float* __restrict__ dW,
            ushort_t* __restrict__ Th, ushort_t* __restrict__ Tl, int R, int C)
{
    __shared__ float t[64][65];
    const int tid = threadIdx.x;
    const int R0 = blockIdx.x * 64, C0 = blockIdx.y * 64;
    const int c = tid & 63, rb = (tid >> 6) * 16;
    for (int i = 0; i < 16; i++) {
        const size_t o = (size_t)(R0 + rb + i) * C + C0 + c;
        t[rb + i][c] = W[o] - LR_C * dW[o];
    }
    __syncthreads();
    const int orr = tid & 63, ob = (tid >> 6) * 16;
    for (int i = 0; i < 16; i++) {
        const int oc = ob + i;
        ushort_t h, l;
        splitf(t[orr][oc], h, l);
        Th[(size_t)(C0 + oc) * R + R0 + orr] = h;
        Tl[(size_t)(C0 + oc) * R + R0 + orr] = l;
    }
}

// elementwise split (no transpose), float4-vectorized
__global__ __launch_bounds__(256)
void ssplit_k(const float* __restrict__ W, ushort_t* __restrict__ Th,
              ushort_t* __restrict__ Tl, int n4)
{
    const int i = blockIdx.x * 256 + threadIdx.x;
    if (i >= n4) return;
    float4 v = *(const float4*)(W + (size_t)i * 4);
    ushort_t h[4], l[4];
    splitf(v.x, h[0], l[0]); splitf(v.y, h[1], l[1]);
    splitf(v.z, h[2], l[2]); splitf(v.w, h[3], l[3]);
    uint2 ph, pl;
    ph.x = (uint_t)h[0] | ((uint_t)h[1] << 16); ph.y = (uint_t)h[2] | ((uint_t)h[3] << 16);
    pl.x = (uint_t)l[0] | ((uint_t)l[1] << 16); pl.y = (uint_t)l[2] | ((uint_t)l[3] << 16);
    *(uint2*)&Th[(size_t)i * 4] = ph;
    *(uint2*)&Tl[(size_t)i * 4] = pl;
}

__global__ __launch_bounds__(256)
void colsum_k(const float* __restrict__ A, float* out, int N, int rows)
{
    const int col = blockIdx.x * 256 + threadIdx.x;
    const int r0 = blockIdx.y * rows;
    float s = 0.f;
    for (int r = 0; r < rows; r++) s += A[(size_t)(r0 + r) * N + col];
    atomicAdd(&out[col], s);
}

// LayerNorm forward + dL/dr0 (row-wise; dr0 may alias r0)
__global__ __launch_bounds__(256)
void ln_fb_k(const float* r0, const float* __restrict__ phi,
             const float* __restrict__ gamma, const float* __restrict__ beta,
             float* recon, float* dr0)
{
    const int lane = threadIdx.x & 63;
    const int wv = threadIdx.x >> 6;
    const int row = blockIdx.x * 4 + wv;
    const size_t base = (size_t)row * U_N + (lane << 2);

    float4 xv = *(const float4*)(r0 + base);
    float s  = xv.x + xv.y + xv.z + xv.w;
    float sq = xv.x * xv.x + xv.y * xv.y + xv.z * xv.z + xv.w * xv.w;
    #pragma unroll
    for (int o = 32; o > 0; o >>= 1) { s += __shfl_xor(s, o); sq += __shfl_xor(sq, o); }
    const float m   = s * (1.0f / U_N);
    const float var = sq * (1.0f / U_N) - m * m;
    const float inv = rsqrtf(var + EPS_C);

    float4 gv = *(const float4*)(gamma + (lane << 2));
    float4 bv = *(const float4*)(beta + (lane << 2));
    float4 pv = *(const float4*)(phi + base);
    float xs[4] = {xv.x, xv.y, xv.z, xv.w};
    float gs[4] = {gv.x, gv.y, gv.z, gv.w};
    float bs[4] = {bv.x, bv.y, bv.z, bv.w};
    float ps[4] = {pv.x, pv.y, pv.z, pv.w};
    float rh[4], dh[4], rc[4];
    float s1 = 0.f, s2 = 0.f;
    const float gscale = 2.0f / ((float)B_N * (float)U_N);
    #pragma unroll
    for (int j = 0; j < 4; j++) {
        rh[j] = (xs[j] - m) * inv;
        rc[j] = rh[j] * gs[j] + bs[j];
        float g2 = gscale * (rc[j] - ps[j]);
        dh[j] = g2 * gs[j];
        s1 += dh[j];
        s2 += dh[j] * rh[j];
    }
    #pragma unroll
    for (int o = 32; o > 0; o >>= 1) { s1 += __shfl_xor(s1, o); s2 += __shfl_xor(s2, o); }
    const float mu1 = s1 * (1.0f / U_N);
    const float mu2 = s2 * (1.0f / U_N);
    float4 ov, dv;
    ov.x = rc[0]; ov.y = rc[1]; ov.z = rc[2]; ov.w = rc[3];
    dv.x = inv * (dh[0] - mu1 - rh[0] * mu2);
    dv.y = inv * (dh[1] - mu1 - rh[1] * mu2);
    dv.z = inv * (dh[2] - mu1 - rh[2] * mu2);
    dv.w = inv * (dh[3] - mu1 - rh[3] * mu2);
    *(float4*)(recon + base) = ov;
    *(float4*)(dr0 + base) = dv;
}

__global__ __launch_bounds__(256)
void bupd_k(const float* __restrict__ b1, const float* __restrict__ db1,
            const float* __restrict__ b2, const float* __restrict__ db2,
            float* __restrict__ b1u, float* __restrict__ b2u)
{
    const int i = blockIdx.x * 256 + threadIdx.x;
    if (i < H_N) b1u[i] = b1[i] - LR_C * db1[i];
    else if (i < H_N + U_N) b2u[i - H_N] = b2[i - H_N] - LR_C * db2[i - H_N];
}

extern "C" void kernel_launch(void* const* d_in, const int* in_sizes, int n_in,
                              void* d_out, int out_size, void* d_ws, size_t ws_size,
                              hipStream_t stream)
{
    const float* x      = (const float*)d_in[0];
    const float* h_prev = (const float*)d_in[1];
    const float* W_phi  = (const float*)d_in[2];
    const float* b_phi  = (const float*)d_in[3];
    const float* W_psi  = (const float*)d_in[4];
    const float* b_psi  = (const float*)d_in[5];
    const float* W1     = (const float*)d_in[6];
    const float* b1     = (const float*)d_in[7];
    const float* W2     = (const float*)d_in[8];
    const float* b2     = (const float*)d_in[9];
    const float* W_g    = (const float*)d_in[10];
    const float* g_bias = (const float*)d_in[11];
    const float* gamma  = (const float*)d_in[12];
    const float* beta   = (const float*)d_in[13];
    const float* W_h    = (const float*)d_in[14];
    const float* h_bias = (const float*)d_in[15];
    float* out = (float*)d_out;

    const size_t BU = (size_t)B_N * U_N;
    const size_t UH = (size_t)U_N * H_N;
    const size_t USH_PLANE = 2 * 131072 + 5 * 262144 + 3 * 65536;
    const size_t USH = 2 * USH_PLANE;

    int G = 1;
    while (G < 256) {
        size_t Bc_ = (size_t)B_N / G;
        size_t fl = 2 * BU + Bc_ * (H_N + 3 * U_N) + 2 * UH + 2 * H_N + 2 * U_N;
        if (fl * 4 + USH * 2 <= ws_size) break;
        G *= 2;
    }
    const int Bc = B_N / G;
    const int CH = (Bc < 1024) ? Bc : 1024;
    const int Z  = Bc / CH;

    float* ws    = (float*)d_ws;
    float* phi   = ws;
    float* recon = phi   + BU;
    float* a1b   = recon + BU;                    // [Bc,H]: a1 -> da -> h2
    float* eb    = a1b   + (size_t)Bc * H_N;      // [Bc,U]: e -> feat
    float* r0b   = eb    + (size_t)Bc * U_N;      // [Bc,U]: r0 -> dr0 -> psi
    float* deb   = r0b   + (size_t)Bc * U_N;      // [Bc,U]
    float* dW1   = deb   + (size_t)Bc * U_N;      // [U,H]
    float* db1   = dW1 + UH;
    float* dW2   = db1 + H_N;                     // [H,U]
    float* db2   = dW2 + UH;
    float* b1u   = db2 + U_N;
    float* b2u   = b1u + H_N;
    ushort_t* us = (ushort_t*)(b2u + U_N);
    ushort_t* WphiT_h = us;                 ushort_t* WphiT_l = WphiT_h + 131072;
    ushort_t* WpsiT_h = WphiT_l + 131072;   ushort_t* WpsiT_l = WpsiT_h + 131072;
    ushort_t* W1T_h   = WpsiT_l + 131072;   ushort_t* W1T_l   = W1T_h + 262144;
    ushort_t* W2T_h   = W1T_l + 262144;     ushort_t* W2T_l   = W2T_h + 262144;
    ushort_t* W2s_h   = W2T_l + 262144;     ushort_t* W2s_l   = W2s_h + 262144;
    ushort_t* W1uT_h  = W2s_l + 262144;     ushort_t* W1uT_l  = W1uT_h + 262144;
    ushort_t* W2uT_h  = W1uT_l + 262144;    ushort_t* W2uT_l  = W2uT_h + 262144;
    ushort_t* WgT_h   = W2uT_l + 262144;    ushort_t* WgT_l   = WgT_h + 65536;
    ushort_t* Wgs_h   = WgT_l + 65536;      ushort_t* Wgs_l   = Wgs_h + 65536;
    ushort_t* WhT_h   = Wgs_l + 65536;      ushort_t* WhT_l   = WhT_h + 65536;

    hipMemsetAsync(dW1, 0, (2 * UH + H_N + U_N) * sizeof(float), stream);

    dim3 blk(256);
    tsplit_k<<<dim3(8, 4),  blk, 0, stream>>>(W_phi, WphiT_h, WphiT_l, 512, 256);
    tsplit_k<<<dim3(8, 4),  blk, 0, stream>>>(W_psi, WpsiT_h, WpsiT_l, 512, 256);
    tsplit_k<<<dim3(4, 16), blk, 0, stream>>>(W1, W1T_h, W1T_l, 256, 1024);
    tsplit_k<<<dim3(16, 4), blk, 0, stream>>>(W2, W2T_h, W2T_l, 1024, 256);
    tsplit_k<<<dim3(4, 4),  blk, 0, stream>>>(W_g, WgT_h, WgT_l, 256, 256);
    tsplit_k<<<dim3(4, 4),  blk, 0, stream>>>(W_h, WhT_h, WhT_l, 256, 256);
    ssplit_k<<<dim3(256),   blk, 0, stream>>>(W2, W2s_h, W2s_l, 65536);
    ssplit_k<<<dim3(64),    blk, 0, stream>>>(W_g, Wgs_h, Wgs_l, 16384);

    // phi = [x|h_prev] @ W_phi + b_phi
    mgemm_k<1,0,EPI_NONE><<<dim3(B_N/128, 2), blk, 0, stream>>>(
        x, h_prev, WphiT_h, WphiT_l, b_phi, nullptr, phi, B_N, U_N, 512);

    // Phase A: inner fwd+bwd, chunked
    for (int c = 0; c < G; c++) {
        const size_t off = (size_t)c * Bc;
        const float* phic = phi + off * U_N;
        mgemm_k<0,0,EPI_NONE><<<dim3(Bc/128, 8), blk, 0, stream>>>(
            phic, nullptr, W1T_h, W1T_l, b1, nullptr, a1b, Bc, H_N, U_N);
        mgemm_k<0,1,EPI_NONE><<<dim3(Bc/128, 2), blk, 0, stream>>>(
            a1b, nullptr, W2T_h, W2T_l, b2, nullptr, eb, Bc, U_N, H_N);
        mgemm_k<0,0,EPI_NONE><<<dim3(Bc/128, 2), blk, 0, stream>>>(
            eb, nullptr, WgT_h, WgT_l, g_bias, nullptr, r0b, Bc, U_N, U_N);
        ln_fb_k<<<dim3(Bc/4), blk, 0, stream>>>(r0b, phic, gamma, beta, recon + off * U_N, r0b);
        mgemm_k<0,0,EPI_NONE><<<dim3(Bc/128, 2), blk, 0, stream>>>(
            r0b, nullptr, Wgs_h, Wgs_l, nullptr, nullptr, deb, Bc, U_N, U_N);
        mgemm_atb_k<1><<<dim3(8, 2, Z), blk, 0, stream>>>(a1b, deb, dW2, H_N, U_N, CH);
        colsum_k<<<dim3(1, Bc/128), blk, 0, stream>>>(deb, db2, U_N, 128);
        mgemm_k<0,0,EPI_DGELU><<<dim3(Bc/128, 8), blk, 0, stream>>>(
            deb, nullptr, W2s_h, W2s_l, nullptr, a1b, a1b, Bc, H_N, U_N);
        mgemm_atb_k<0><<<dim3(2, 8, Z), blk, 0, stream>>>(phic, a1b, dW1, U_N, H_N, CH);
        colsum_k<<<dim3(4, Bc/128), blk, 0, stream>>>(a1b, db1, H_N, 128);
    }

    // Phase B: updated params (transposed + split)
    bupd_k<<<dim3(5), blk, 0, stream>>>(b1, db1, b2, db2, b1u, b2u);
    tupd_k<<<dim3(4, 16), blk, 0, stream>>>(W1, dW1, W1uT_h, W1uT_l, 256, 1024);
    tupd_k<<<dim3(16, 4), blk, 0, stream>>>(W2, dW2, W2uT_h, W2uT_l, 1024, 256);

    // Phase C
    for (int c = 0; c < G; c++) {
        const size_t off = (size_t)c * Bc;
        mgemm_k<1,0,EPI_NONE><<<dim3(Bc/128, 2), blk, 0, stream>>>(
            x + off * 256, h_prev + off * U_N, WpsiT_h, WpsiT_l, b_psi, nullptr, r0b, Bc, U_N, 512);
        mgemm_k<0,0,EPI_GELU><<<dim3(Bc/128, 8), blk, 0, stream>>>(
            r0b, nullptr, W1uT_h, W1uT_l, b1u, nullptr, a1b, Bc, H_N, U_N);
        mgemm_k<0,0,EPI_ADDS><<<dim3(Bc/128, 2), blk, 0, stream>>>(
            a1b, nullptr, W2uT_h, W2uT_l, b2u, recon + off * U_N, eb, Bc, U_N, H_N);
        mgemm_k<0,0,EPI_NONE><<<dim3(Bc/128, 2), blk, 0, stream>>>(
            eb, nullptr, WhT_h, WhT_l, h_bias, nullptr, out + off * U_N, Bc, U_N, U_N);
    }
}

// Round 5
// 1545.221 us; speedup vs baseline: 1.8839x; 1.0554x over previous
//
#include <hip/hip_runtime.h>
#include <math.h>

#define B_N 32768
#define U_N 256
#define H_N 1024
#define LR_C 0.01f
#define EPS_C 1e-3f

typedef unsigned short ushort_t;
typedef unsigned int uint_t;
using frag8 = __attribute__((ext_vector_type(8))) short;   // 8 bf16 = 4 VGPR
using f32x4 = __attribute__((ext_vector_type(4))) float;   // MFMA acc

__device__ __forceinline__ float gelu_f(float x) {
    return 0.5f * x * (1.0f + erff(x * 0.7071067811865475f));
}
__device__ __forceinline__ float dgelu_f(float x) {
    float c = 0.5f * (1.0f + erff(x * 0.7071067811865475f));
    float p = 0.3989422804014327f * expf(-0.5f * x * x);
    return c + x * p;
}

// fp32 -> (hi, lo) bf16 pair. hi = truncation (residual exact), lo = RNE(residual).
__device__ __forceinline__ void splitf(float v, ushort_t& h, ushort_t& l) {
    uint_t u = __float_as_uint(v);
    h = (ushort_t)(u >> 16);
    float r = v - __uint_as_float(u & 0xFFFF0000u);
    uint_t ru = __float_as_uint(r);
    l = (ushort_t)((ru + 0x7FFFu + ((ru >> 16) & 1u)) >> 16);
}
// fp32 -> bf16 RNE (for 1-pass gradient-path GEMMs)
__device__ __forceinline__ ushort_t cvt_rne(float v) {
    uint_t u = __float_as_uint(v);
    return (ushort_t)((u + 0x7FFFu + ((u >> 16) & 1u)) >> 16);
}

#define EPI_NONE 0
#define EPI_GELU 1
#define EPI_DGELU 2
#define EPI_ADDS 3

// ---------------------------------------------------------------------------
// MFMA GEMM: C[M,N] = epi( A[M,K] @ B[K,N] + bias ), B given as BT = B^T [N,K]
// pre-split into bf16 hi/lo planes. PASSES=3: split-bf16 (hh+hl+lh, fp32-class).
// PASSES=1: plain bf16 (gradient path — LR*dW makes the error negligible).
// ---------------------------------------------------------------------------
template<int ACONCAT, int AGELU, int EPI, int PASSES>
__global__ __launch_bounds__(256)
void mgemm_k(const float* A, const float* A2,
             const ushort_t* __restrict__ BTh, const ushort_t* __restrict__ BTl,
             const float* __restrict__ bias, const float* X, float* C,
             int M, int N, int K)
{
    __shared__ ushort_t Ah[128 * 40];
    __shared__ ushort_t Bh[128 * 40];
    __shared__ ushort_t Al[(PASSES == 3) ? 128 * 40 : 8];
    __shared__ ushort_t Bl[(PASSES == 3) ? 128 * 40 : 8];
    const int tid = threadIdx.x;
    const int m0 = blockIdx.x * 128, n0 = blockIdx.y * 128;
    const int lane = tid & 63, w = tid >> 6;
    const int wm = (w & 1) * 64, wn = (w >> 1) * 64;
    const int fr = lane & 15, fq = lane >> 4;
    const int sr = tid >> 1;               // staging row 0..127
    const int sk = (tid & 1) * 16;         // staging k offset 0/16

    f32x4 acc[4][4];
    #pragma unroll
    for (int i = 0; i < 4; i++)
        #pragma unroll
        for (int j = 0; j < 4; j++) acc[i][j] = (f32x4){0.f, 0.f, 0.f, 0.f};

    for (int k0 = 0; k0 < K; k0 += 32) {
        // ---- stage A: 128x32 fp32 -> bf16 (hi/lo or RNE) ----
        #pragma unroll
        for (int g = 0; g < 2; g++) {
            uint4 qh, qa;
            uint_t ph[4], pl[4];
            #pragma unroll
            for (int c = 0; c < 2; c++) {
                const int ak = k0 + sk + g * 8 + c * 4;
                const float* ap;
                if (ACONCAT) ap = (ak < 256) ? (A + (size_t)(m0 + sr) * 256 + ak)
                                             : (A2 + (size_t)(m0 + sr) * 256 + (ak - 256));
                else         ap = A + (size_t)(m0 + sr) * K + ak;
                float4 v = *(const float4*)ap;
                if (AGELU) { v.x = gelu_f(v.x); v.y = gelu_f(v.y);
                             v.z = gelu_f(v.z); v.w = gelu_f(v.w); }
                if (PASSES == 3) {
                    ushort_t h0,h1,h2,h3,l0,l1,l2,l3;
                    splitf(v.x,h0,l0); splitf(v.y,h1,l1); splitf(v.z,h2,l2); splitf(v.w,h3,l3);
                    ph[c*2]   = (uint_t)h0 | ((uint_t)h1 << 16);
                    ph[c*2+1] = (uint_t)h2 | ((uint_t)h3 << 16);
                    pl[c*2]   = (uint_t)l0 | ((uint_t)l1 << 16);
                    pl[c*2+1] = (uint_t)l2 | ((uint_t)l3 << 16);
                } else {
                    ph[c*2]   = (uint_t)cvt_rne(v.x) | ((uint_t)cvt_rne(v.y) << 16);
                    ph[c*2+1] = (uint_t)cvt_rne(v.z) | ((uint_t)cvt_rne(v.w) << 16);
                }
            }
            qh.x = ph[0]; qh.y = ph[1]; qh.z = ph[2]; qh.w = ph[3];
            *(uint4*)&Ah[sr * 40 + sk + g * 8] = qh;
            if (PASSES == 3) {
                qa.x = pl[0]; qa.y = pl[1]; qa.z = pl[2]; qa.w = pl[3];
                *(uint4*)&Al[sr * 40 + sk + g * 8] = qa;
            }
        }
        // ---- stage B: copy pre-split bf16 planes ----
        {
            const size_t bo = (size_t)(n0 + sr) * K + k0 + sk;
            *(uint4*)&Bh[sr * 40 + sk]     = *(const uint4*)&BTh[bo];
            *(uint4*)&Bh[sr * 40 + sk + 8] = *(const uint4*)&BTh[bo + 8];
            if (PASSES == 3) {
                *(uint4*)&Bl[sr * 40 + sk]     = *(const uint4*)&BTl[bo];
                *(uint4*)&Bl[sr * 40 + sk + 8] = *(const uint4*)&BTl[bo + 8];
            }
        }
        __syncthreads();

        frag8 afh[4], afl[4], bfh[4], bfl[4];
        #pragma unroll
        for (int i = 0; i < 4; i++) {
            const int ar = wm + i * 16 + fr;
            afh[i] = *(frag8*)&Ah[ar * 40 + fq * 8];
            if (PASSES == 3) afl[i] = *(frag8*)&Al[ar * 40 + fq * 8];
        }
        #pragma unroll
        for (int j = 0; j < 4; j++) {
            const int br = wn + j * 16 + fr;
            bfh[j] = *(frag8*)&Bh[br * 40 + fq * 8];
            if (PASSES == 3) bfl[j] = *(frag8*)&Bl[br * 40 + fq * 8];
        }
        #pragma unroll
        for (int i = 0; i < 4; i++)
            #pragma unroll
            for (int j = 0; j < 4; j++) {
                acc[i][j] = __builtin_amdgcn_mfma_f32_16x16x32_bf16(afh[i], bfh[j], acc[i][j], 0, 0, 0);
                if (PASSES == 3) {
                    acc[i][j] = __builtin_amdgcn_mfma_f32_16x16x32_bf16(afh[i], bfl[j], acc[i][j], 0, 0, 0);
                    acc[i][j] = __builtin_amdgcn_mfma_f32_16x16x32_bf16(afl[i], bfh[j], acc[i][j], 0, 0, 0);
                }
            }
        __syncthreads();
    }

    float bv[4] = {0.f, 0.f, 0.f, 0.f};
    if (bias != nullptr)
        #pragma unroll
        for (int j = 0; j < 4; j++) bv[j] = bias[n0 + wn + j * 16 + fr];
    #pragma unroll
    for (int i = 0; i < 4; i++)
        #pragma unroll
        for (int j = 0; j < 4; j++) {
            const int col = n0 + wn + j * 16 + fr;
            #pragma unroll
            for (int r = 0; r < 4; r++) {
                const int row = m0 + wm + i * 16 + fq * 4 + r;
                const size_t off = (size_t)row * N + col;
                float c = acc[i][j][r] + bv[j];
                if (EPI == EPI_GELU)       c = gelu_f(c);
                else if (EPI == EPI_DGELU) c = c * dgelu_f(X[off]);
                else if (EPI == EPI_ADDS)  c = c + 0.1f * X[off];
                C[off] = c;
            }
        }
}

// ---------------------------------------------------------------------------
// MFMA TN GEMM (weight grads): C[M,N] += sum_k A[k,m] * B[k,n] over K-chunk.
// 1-pass bf16 (dW is scaled by LR=0.01 — bf16 error is negligible).
// Pitch 44 + b64 frag reads: lane bank stride 22 -> 16 distinct banks.
// ---------------------------------------------------------------------------
template<int AGELU>
__global__ __launch_bounds__(256)
void mgemm_atb_k(const float* A, const float* Bg, float* C,
                 int M, int N, int CH)
{
    __shared__ ushort_t Ah[128 * 44];
    __shared__ ushort_t Bh[128 * 44];
    const int tid = threadIdx.x;
    const int m0 = blockIdx.x * 128, n0 = blockIdx.y * 128;
    const int kbeg = blockIdx.z * CH;
    const int lane = tid & 63, w = tid >> 6;
    const int wm = (w & 1) * 64, wn = (w >> 1) * 64;
    const int fr = lane & 15, fq = lane >> 4;
    const int cp = (tid >> 2) * 2;     // col pair base: 0,2,..,126
    const int pg = (tid & 3) * 8;      // k-row group base: 0,8,16,24

    f32x4 acc[4][4];
    #pragma unroll
    for (int i = 0; i < 4; i++)
        #pragma unroll
        for (int j = 0; j < 4; j++) acc[i][j] = (f32x4){0.f, 0.f, 0.f, 0.f};

    for (int k0 = kbeg; k0 < kbeg + CH; k0 += 32) {
        // ---- stage A^T: cols {cp,cp+1}, k-rows pg..pg+7 ----
        {
            uint_t pa[4], pb[4];
            #pragma unroll
            for (int d = 0; d < 4; d++) {
                float2 va = *(const float2*)(A + (size_t)(k0 + pg + 2*d)     * M + m0 + cp);
                float2 vb = *(const float2*)(A + (size_t)(k0 + pg + 2*d + 1) * M + m0 + cp);
                if (AGELU) { va.x = gelu_f(va.x); va.y = gelu_f(va.y);
                             vb.x = gelu_f(vb.x); vb.y = gelu_f(vb.y); }
                pa[d] = (uint_t)cvt_rne(va.x) | ((uint_t)cvt_rne(vb.x) << 16);
                pb[d] = (uint_t)cvt_rne(va.y) | ((uint_t)cvt_rne(vb.y) << 16);
            }
            *(uint2*)&Ah[cp * 44 + pg]           = (uint2){pa[0], pa[1]};
            *(uint2*)&Ah[cp * 44 + pg + 4]       = (uint2){pa[2], pa[3]};
            *(uint2*)&Ah[(cp + 1) * 44 + pg]     = (uint2){pb[0], pb[1]};
            *(uint2*)&Ah[(cp + 1) * 44 + pg + 4] = (uint2){pb[2], pb[3]};
        }
        // ---- stage B^T ----
        {
            uint_t pa[4], pb[4];
            #pragma unroll
            for (int d = 0; d < 4; d++) {
                float2 va = *(const float2*)(Bg + (size_t)(k0 + pg + 2*d)     * N + n0 + cp);
                float2 vb = *(const float2*)(Bg + (size_t)(k0 + pg + 2*d + 1) * N + n0 + cp);
                pa[d] = (uint_t)cvt_rne(va.x) | ((uint_t)cvt_rne(vb.x) << 16);
                pb[d] = (uint_t)cvt_rne(va.y) | ((uint_t)cvt_rne(vb.y) << 16);
            }
            *(uint2*)&Bh[cp * 44 + pg]           = (uint2){pa[0], pa[1]};
            *(uint2*)&Bh[cp * 44 + pg + 4]       = (uint2){pa[2], pa[3]};
            *(uint2*)&Bh[(cp + 1) * 44 + pg]     = (uint2){pb[0], pb[1]};
            *(uint2*)&Bh[(cp + 1) * 44 + pg + 4] = (uint2){pb[2], pb[3]};
        }
        __syncthreads();

        frag8 af[4], bf[4];
        #pragma unroll
        for (int i = 0; i < 4; i++) {
            const int a = (wm + i * 16 + fr) * 44 + fq * 8;
            *(uint2*)&af[i]       = *(uint2*)&Ah[a];
            *((uint2*)&af[i] + 1) = *(uint2*)&Ah[a + 4];
        }
        #pragma unroll
        for (int j = 0; j < 4; j++) {
            const int a = (wn + j * 16 + fr) * 44 + fq * 8;
            *(uint2*)&bf[j]       = *(uint2*)&Bh[a];
            *((uint2*)&bf[j] + 1) = *(uint2*)&Bh[a + 4];
        }
        #pragma unroll
        for (int i = 0; i < 4; i++)
            #pragma unroll
            for (int j = 0; j < 4; j++)
                acc[i][j] = __builtin_amdgcn_mfma_f32_16x16x32_bf16(af[i], bf[j], acc[i][j], 0, 0, 0);
        __syncthreads();
    }
    #pragma unroll
    for (int i = 0; i < 4; i++)
        #pragma unroll
        for (int j = 0; j < 4; j++) {
            const int col = n0 + wn + j * 16 + fr;
            #pragma unroll
            for (int r = 0; r < 4; r++) {
                const int row = m0 + wm + i * 16 + fq * 4 + r;
                atomicAdd(&C[(size_t)row * N + col], acc[i][j][r]);
            }
        }
}

// transpose + split: W [R,C] fp32 -> Th/Tl [C,R] bf16 planes
__global__ __launch_bounds__(256)
void tsplit_k(const float* __restrict__ W, ushort_t* __restrict__ Th,
              ushort_t* __restrict__ Tl, int R, int C)
{
    __shared__ float t[64][65];
    const int tid = threadIdx.x;
    const int R0 = blockIdx.x * 64, C0 = blockIdx.y * 64;
    const int c = tid & 63, rb = (tid >> 6) * 16;
    for (int i = 0; i < 16; i++)
        t[rb + i][c] = W[(size_t)(R0 + rb + i) * C + C0 + c];
    __syncthreads();
    const int orr = tid & 63, ob = (tid >> 6) * 16;
    for (int i = 0; i < 16; i++) {
        const int oc = ob + i;
        ushort_t h, l;
        splitf(t[orr][oc], h, l);
        Th[(size_t)(C0 + oc) * R + R0 + orr] = h;
        Tl[(size_t)(C0 + oc) * R + R0 + orr] = l;
    }
}

// transpose + SGD update + split: (W - LR*dW) [R,C] -> Th/Tl [C,R]
__global__ __launch_bounds__(256)
void tupd_k(const float* __restrict__ W, const float* __restrict__ dW,
            ushort_t* __restrict__ Th, ushort_t* __restrict__ Tl, int R, int C)
{
    __shared__ float t[64][65];
    const int tid = threadIdx.x;
    const int R0 = blockIdx.x * 64, C0 = blockIdx.y * 64;
    const int c = tid & 63, rb = (tid >> 6) * 16;
    for (int i = 0; i < 16; i++) {
        const size_t o = (size_t)(R0 + rb + i) * C + C0 + c;
        t[rb + i][c] = W[o] - LR_C * dW[o];
    }
    __syncthreads();
    const int orr = tid & 63, ob = (tid >> 6) * 16;
    for (int i = 0; i < 16; i++) {
        const int oc = ob + i;
        ushort_t h, l;
        splitf(t[orr][oc], h, l);
        Th[(size_t)(C0 + oc) * R + R0 + orr] = h;
        Tl[(size_t)(C0 + oc) * R + R0 + orr] = l;
    }
}

// elementwise split (no transpose), float4-vectorized
__global__ __launch_bounds__(256)
void ssplit_k(const float* __restrict__ W, ushort_t* __restrict__ Th,
              ushort_t* __restrict__ Tl, int n4)
{
    const int i = blockIdx.x * 256 + threadIdx.x;
    if (i >= n4) return;
    float4 v = *(const float4*)(W + (size_t)i * 4);
    ushort_t h[4], l[4];
    splitf(v.x, h[0], l[0]); splitf(v.y, h[1], l[1]);
    splitf(v.z, h[2], l[2]); splitf(v.w, h[3], l[3]);
    uint2 ph, pl;
    ph.x = (uint_t)h[0] | ((uint_t)h[1] << 16); ph.y = (uint_t)h[2] | ((uint_t)h[3] << 16);
    pl.x = (uint_t)l[0] | ((uint_t)l[1] << 16); pl.y = (uint_t)l[2] | ((uint_t)l[3] << 16);
    *(uint2*)&Th[(size_t)i * 4] = ph;
    *(uint2*)&Tl[(size_t)i * 4] = pl;
}

__global__ __launch_bounds__(256)
void colsum_k(const float* __restrict__ A, float* out, int N, int rows)
{
    const int col = blockIdx.x * 256 + threadIdx.x;
    const int r0 = blockIdx.y * rows;
    float s = 0.f;
    for (int r = 0; r < rows; r++) s += A[(size_t)(r0 + r) * N + col];
    atomicAdd(&out[col], s);
}

// LayerNorm forward + dL/dr0 (row-wise; dr0 may alias r0)
__global__ __launch_bounds__(256)
void ln_fb_k(const float* r0, const float* __restrict__ phi,
             const float* __restrict__ gamma, const float* __restrict__ beta,
             float* recon, float* dr0)
{
    const int lane = threadIdx.x & 63;
    const int wv = threadIdx.x >> 6;
    const int row = blockIdx.x * 4 + wv;
    const size_t base = (size_t)row * U_N + (lane << 2);

    float4 xv = *(const float4*)(r0 + base);
    float s  = xv.x + xv.y + xv.z + xv.w;
    float sq = xv.x * xv.x + xv.y * xv.y + xv.z * xv.z + xv.w * xv.w;
    #pragma unroll
    for (int o = 32; o > 0; o >>= 1) { s += __shfl_xor(s, o); sq += __shfl_xor(sq, o); }
    const float m   = s * (1.0f / U_N);
    const float var = sq * (1.0f / U_N) - m * m;
    const float inv = rsqrtf(var + EPS_C);

    float4 gv = *(const float4*)(gamma + (lane << 2));
    float4 bv = *(const float4*)(beta + (lane << 2));
    float4 pv = *(const float4*)(phi + base);
    float xs[4] = {xv.x, xv.y, xv.z, xv.w};
    float gs[4] = {gv.x, gv.y, gv.z, gv.w};
    float bs[4] = {bv.x, bv.y, bv.z, bv.w};
    float ps[4] = {pv.x, pv.y, pv.z, pv.w};
    float rh[4], dh[4], rc[4];
    float s1 = 0.f, s2 = 0.f;
    const float gscale = 2.0f / ((float)B_N * (float)U_N);
    #pragma unroll
    for (int j = 0; j < 4; j++) {
        rh[j] = (xs[j] - m) * inv;
        rc[j] = rh[j] * gs[j] + bs[j];
        float g2 = gscale * (rc[j] - ps[j]);
        dh[j] = g2 * gs[j];
        s1 += dh[j];
        s2 += dh[j] * rh[j];
    }
    #pragma unroll
    for (int o = 32; o > 0; o >>= 1) { s1 += __shfl_xor(s1, o); s2 += __shfl_xor(s2, o); }
    const float mu1 = s1 * (1.0f / U_N);
    const float mu2 = s2 * (1.0f / U_N);
    float4 ov, dv;
    ov.x = rc[0]; ov.y = rc[1]; ov.z = rc[2]; ov.w = rc[3];
    dv.x = inv * (dh[0] - mu1 - rh[0] * mu2);
    dv.y = inv * (dh[1] - mu1 - rh[1] * mu2);
    dv.z = inv * (dh[2] - mu1 - rh[2] * mu2);
    dv.w = inv * (dh[3] - mu1 - rh[3] * mu2);
    *(float4*)(recon + base) = ov;
    *(float4*)(dr0 + base) = dv;
}

__global__ __launch_bounds__(256)
void bupd_k(const float* __restrict__ b1, const float* __restrict__ db1,
            const float* __restrict__ b2, const float* __restrict__ db2,
            float* __restrict__ b1u, float* __restrict__ b2u)
{
    const int i = blockIdx.x * 256 + threadIdx.x;
    if (i < H_N) b1u[i] = b1[i] - LR_C * db1[i];
    else if (i < H_N + U_N) b2u[i - H_N] = b2[i - H_N] - LR_C * db2[i - H_N];
}

extern "C" void kernel_launch(void* const* d_in, const int* in_sizes, int n_in,
                              void* d_out, int out_size, void* d_ws, size_t ws_size,
                              hipStream_t stream)
{
    const float* x      = (const float*)d_in[0];
    const float* h_prev = (const float*)d_in[1];
    const float* W_phi  = (const float*)d_in[2];
    const float* b_phi  = (const float*)d_in[3];
    const float* W_psi  = (const float*)d_in[4];
    const float* b_psi  = (const float*)d_in[5];
    const float* W1     = (const float*)d_in[6];
    const float* b1     = (const float*)d_in[7];
    const float* W2     = (const float*)d_in[8];
    const float* b2     = (const float*)d_in[9];
    const float* W_g    = (const float*)d_in[10];
    const float* g_bias = (const float*)d_in[11];
    const float* gamma  = (const float*)d_in[12];
    const float* beta   = (const float*)d_in[13];
    const float* W_h    = (const float*)d_in[14];
    const float* h_bias = (const float*)d_in[15];
    float* out = (float*)d_out;

    const size_t BU = (size_t)B_N * U_N;
    const size_t UH = (size_t)U_N * H_N;
    const size_t USH_PLANE = 2 * 131072 + 5 * 262144 + 3 * 65536;
    const size_t USH = 2 * USH_PLANE;

    int G = 1;
    while (G < 256) {
        size_t Bc_ = (size_t)B_N / G;
        size_t fl = 2 * BU + Bc_ * (H_N + 3 * U_N) + 2 * UH + 2 * H_N + 2 * U_N;
        if (fl * 4 + USH * 2 <= ws_size) break;
        G *= 2;
    }
    const int Bc = B_N / G;
    const int CH = (Bc < 512) ? Bc : 512;
    const int Z  = Bc / CH;

    float* ws    = (float*)d_ws;
    float* phi   = ws;
    float* recon = phi   + BU;
    float* a1b   = recon + BU;                    // [Bc,H]: a1 -> da -> h2
    float* eb    = a1b   + (size_t)Bc * H_N;      // [Bc,U]: e -> feat
    float* r0b   = eb    + (size_t)Bc * U_N;      // [Bc,U]: r0 -> dr0 -> psi
    float* deb   = r0b   + (size_t)Bc * U_N;      // [Bc,U]
    float* dW1   = deb   + (size_t)Bc * U_N;      // [U,H]
    float* db1   = dW1 + UH;
    float* dW2   = db1 + H_N;                     // [H,U]
    float* db2   = dW2 + UH;
    float* b1u   = db2 + U_N;
    float* b2u   = b1u + H_N;
    ushort_t* us = (ushort_t*)(b2u + U_N);
    ushort_t* WphiT_h = us;                 ushort_t* WphiT_l = WphiT_h + 131072;
    ushort_t* WpsiT_h = WphiT_l + 131072;   ushort_t* WpsiT_l = WpsiT_h + 131072;
    ushort_t* W1T_h   = WpsiT_l + 131072;   ushort_t* W1T_l   = W1T_h + 262144;
    ushort_t* W2T_h   = W1T_l + 262144;     ushort_t* W2T_l   = W2T_h + 262144;
    ushort_t* W2s_h   = W2T_l + 262144;     ushort_t* W2s_l   = W2s_h + 262144;
    ushort_t* W1uT_h  = W2s_l + 262144;     ushort_t* W1uT_l  = W1uT_h + 262144;
    ushort_t* W2uT_h  = W1uT_l + 262144;    ushort_t* W2uT_l  = W2uT_h + 262144;
    ushort_t* WgT_h   = W2uT_l + 262144;    ushort_t* WgT_l   = WgT_h + 65536;
    ushort_t* Wgs_h   = WgT_l + 65536;      ushort_t* Wgs_l   = Wgs_h + 65536;
    ushort_t* WhT_h   = Wgs_l + 65536;      ushort_t* WhT_l   = WhT_h + 65536;

    hipMemsetAsync(dW1, 0, (2 * UH + H_N + U_N) * sizeof(float), stream);

    dim3 blk(256);
    tsplit_k<<<dim3(8, 4),  blk, 0, stream>>>(W_phi, WphiT_h, WphiT_l, 512, 256);
    tsplit_k<<<dim3(8, 4),  blk, 0, stream>>>(W_psi, WpsiT_h, WpsiT_l, 512, 256);
    tsplit_k<<<dim3(4, 16), blk, 0, stream>>>(W1, W1T_h, W1T_l, 256, 1024);
    tsplit_k<<<dim3(16, 4), blk, 0, stream>>>(W2, W2T_h, W2T_l, 1024, 256);
    tsplit_k<<<dim3(4, 4),  blk, 0, stream>>>(W_g, WgT_h, WgT_l, 256, 256);
    tsplit_k<<<dim3(4, 4),  blk, 0, stream>>>(W_h, WhT_h, WhT_l, 256, 256);
    ssplit_k<<<dim3(256),   blk, 0, stream>>>(W2, W2s_h, W2s_l, 65536);
    ssplit_k<<<dim3(64),    blk, 0, stream>>>(W_g, Wgs_h, Wgs_l, 16384);

    // phi = [x|h_prev] @ W_phi + b_phi
    mgemm_k<1,0,EPI_NONE,3><<<dim3(B_N/128, 2), blk, 0, stream>>>(
        x, h_prev, WphiT_h, WphiT_l, b_phi, nullptr, phi, B_N, U_N, 512);

    // Phase A: inner fwd+bwd, chunked
    for (int c = 0; c < G; c++) {
        const size_t off = (size_t)c * Bc;
        const float* phic = phi + off * U_N;
        mgemm_k<0,0,EPI_NONE,3><<<dim3(Bc/128, 8), blk, 0, stream>>>(
            phic, nullptr, W1T_h, W1T_l, b1, nullptr, a1b, Bc, H_N, U_N);
        mgemm_k<0,1,EPI_NONE,3><<<dim3(Bc/128, 2), blk, 0, stream>>>(
            a1b, nullptr, W2T_h, W2T_l, b2, nullptr, eb, Bc, U_N, H_N);
        mgemm_k<0,0,EPI_NONE,3><<<dim3(Bc/128, 2), blk, 0, stream>>>(
            eb, nullptr, WgT_h, WgT_l, g_bias, nullptr, r0b, Bc, U_N, U_N);
        ln_fb_k<<<dim3(Bc/4), blk, 0, stream>>>(r0b, phic, gamma, beta, recon + off * U_N, r0b);
        // gradient path: 1-pass bf16 (error scaled by LR)
        mgemm_k<0,0,EPI_NONE,1><<<dim3(Bc/128, 2), blk, 0, stream>>>(
            r0b, nullptr, Wgs_h, Wgs_l, nullptr, nullptr, deb, Bc, U_N, U_N);
        mgemm_atb_k<1><<<dim3(8, 2, Z), blk, 0, stream>>>(a1b, deb, dW2, H_N, U_N, CH);
        colsum_k<<<dim3(1, Bc/128), blk, 0, stream>>>(deb, db2, U_N, 128);
        mgemm_k<0,0,EPI_DGELU,1><<<dim3(Bc/128, 8), blk, 0, stream>>>(
            deb, nullptr, W2s_h, W2s_l, nullptr, a1b, a1b, Bc, H_N, U_N);
        mgemm_atb_k<0><<<dim3(2, 8, Z), blk, 0, stream>>>(phic, a1b, dW1, U_N, H_N, CH);
        colsum_k<<<dim3(4, Bc/128), blk, 0, stream>>>(a1b, db1, H_N, 128);
    }

    // Phase B: updated params (transposed + split)
    bupd_k<<<dim3(5), blk, 0, stream>>>(b1, db1, b2, db2, b1u, b2u);
    tupd_k<<<dim3(4, 16), blk, 0, stream>>>(W1, dW1, W1uT_h, W1uT_l, 256, 1024);
    tupd_k<<<dim3(16, 4), blk, 0, stream>>>(W2, dW2, W2uT_h, W2uT_l, 1024, 256);

    // Phase C
    for (int c = 0; c < G; c++) {
        const size_t off = (size_t)c * Bc;
        mgemm_k<1,0,EPI_NONE,3><<<dim3(Bc/128, 2), blk, 0, stream>>>(
            x + off * 256, h_prev + off * U_N, WpsiT_h, WpsiT_l, b_psi, nullptr, r0b, Bc, U_N, 512);
        mgemm_k<0,0,EPI_GELU,3><<<dim3(Bc/128, 8), blk, 0, stream>>>(
            r0b, nullptr, W1uT_h, W1uT_l, b1u, nullptr, a1b, Bc, H_N, U_N);
        mgemm_k<0,0,EPI_ADDS,3><<<dim3(Bc/128, 2), blk, 0, stream>>>(
            a1b, nullptr, W2uT_h, W2uT_l, b2u, recon + off * U_N, eb, Bc, U_N, H_N);
        mgemm_k<0,0,EPI_NONE,3><<<dim3(Bc/128, 2), blk, 0, stream>>>(
            eb, nullptr, WhT_h, WhT_l, h_bias, nullptr, out + off * U_N, Bc, U_N, U_N);
    }
}